// Round 8
// baseline (145.935 us; speedup 1.0000x reference)
//
#include <hip/hip_runtime.h>
#include <hip/hip_bf16.h>

typedef __bf16 bf16x8 __attribute__((ext_vector_type(8)));
typedef _Float16 half8 __attribute__((ext_vector_type(8)));
typedef _Float16 half2v __attribute__((ext_vector_type(2)));
typedef short s16x2 __attribute__((ext_vector_type(2)));
typedef float f32x4 __attribute__((ext_vector_type(4)));
typedef float f32x16 __attribute__((ext_vector_type(16)));

#define NROW 3072
#define NF 512            // IN_F == H*D == 512
#define NH 8
#define ND 64
#define GEMM_BLOCKS 384
#define BP_BLOCKS 1152    // 3072 rows x 96 segs / 256 thr

// Order-preserving float<->uint key for atomicMax over signed floats.
// key 0 is below every encoded finite float -> memset(0) is a valid init.
__device__ __forceinline__ unsigned gat_enc_key(float f) {
    unsigned u = __float_as_uint(f);
    return (f < 0.f) ? ~u : (u | 0x80000000u);
}
__device__ __forceinline__ float gat_dec_key(unsigned k) {
    unsigned u = (k & 0x80000000u) ? (k ^ 0x80000000u) : ~k;
    return __uint_as_float(u);
}

// ---------------------------------------------------------------------------
// Stage 1 (fused): blocks 0..383: h = x @ W^T, 64x64 block tiles, 4 waves of
// 32x32 mfma_32x32x16_bf16. THIS ROUND: NO LDS / NO BARRIERS in the K-loop —
// the 32x32x16 A/B fragment is exactly a per-lane row slice
// (row = tile + l31, k = half*8..+8 = 2 float4 global loads), so each wave
// loads fragments straight from global and converts in-register. R7 proved
// source-level pipelining dies at __syncthreads (compiler emits vmcnt(0)
// drain before every s_barrier); with a barrier-free reg-only loop the
// compiler pipelines with counted vmcnt and free-running waves hide L2
// latency. LDS now only for the small epilogue transpose (11 KB).
// Blocks 384..1535: bitpack (adj>0 || j==i), per-thread int4 loads.
// Epilogue: hT store + fused e_src/e_dst + per-head atomicMax.
// ---------------------------------------------------------------------------
__global__ __launch_bounds__(256) void gat_gemm_bp(const float* __restrict__ x,
                                                   const float* __restrict__ W,
                                                   _Float16* __restrict__ hT,
                                                   const int* __restrict__ adj,
                                                   unsigned* __restrict__ bits,
                                                   const float* __restrict__ a_src,
                                                   const float* __restrict__ a_dst,
                                                   float* __restrict__ e_srcT,
                                                   float* __restrict__ e_dstT,
                                                   unsigned* __restrict__ maxkey) {
    __shared__ __align__(16) _Float16 tts[4 * 1280];   // 4 waves x 32x40 transpose
    __shared__ float ered[2][2][2][32];                // [src/dst][wr][wc][row]

    if (blockIdx.x >= GEMM_BLOCKS) {
        // ---- bitpack path: thread owns one 32-j segment (128 B contiguous) ----
        int g = (blockIdx.x - GEMM_BLOCKS) * 256 + threadIdx.x;   // 0..294911
        int row = g / 96;
        int seg = g - row * 96;
        const int* p = adj + row * NROW + seg * 32;
        unsigned w = 0;
#pragma unroll
        for (int q = 0; q < 8; ++q) {
            int4 v = *reinterpret_cast<const int4*>(p + q * 4);
            unsigned b0 = (v.x > 0) ? 1u : 0u;
            unsigned b1 = (v.y > 0) ? 2u : 0u;
            unsigned b2 = (v.z > 0) ? 4u : 0u;
            unsigned b3 = (v.w > 0) ? 8u : 0u;
            w |= (b0 | b1 | b2 | b3) << (q * 4);
        }
        int d = row - seg * 32;
        if ((unsigned)d < 32u) w |= 1u << d;      // diagonal (j == i)
        bits[g] = w;                              // g == row*96 + seg
        return;
    }

    // ---- gemm path ----
    int b = blockIdx.x;                 // 48 i-panels x 8 o-groups (= heads)
    int i0 = (b >> 3) * 64;
    int o0 = (b & 7) * 64;
    int head = b & 7;
    int tid = threadIdx.x;
    int wave = tid >> 6;
    int lane = tid & 63;
    int half = lane >> 5;
    int l31 = lane & 31;
    int wr = wave >> 1;                 // i sub-tile (0/1)
    int wc = wave & 1;                  // o sub-tile (0/1)

    // per-lane fragment source rows (row stride 2 KB; lane pairs l/l+32
    // share a 128-B line; k-steps walk each row -> L1/L2 hits after first).
    const float* xr = x + (long)(i0 + wr * 32 + l31) * NF + half * 8;
    const float* wp = W + (long)(o0 + wc * 32 + l31) * NF + half * 8;

    f32x16 acc = {};
    float4 a0 = *reinterpret_cast<const float4*>(xr);
    float4 a1 = *reinterpret_cast<const float4*>(xr + 4);
    float4 b0 = *reinterpret_cast<const float4*>(wp);
    float4 b1 = *reinterpret_cast<const float4*>(wp + 4);
#pragma unroll
    for (int c = 0; c < 32; ++c) {
        float4 na0, na1, nb0, nb1;
        if (c < 31) {
            na0 = *reinterpret_cast<const float4*>(xr + (c + 1) * 16);
            na1 = *reinterpret_cast<const float4*>(xr + (c + 1) * 16 + 4);
            nb0 = *reinterpret_cast<const float4*>(wp + (c + 1) * 16);
            nb1 = *reinterpret_cast<const float4*>(wp + (c + 1) * 16 + 4);
        }
        bf16x8 af = { (__bf16)a0.x, (__bf16)a0.y, (__bf16)a0.z, (__bf16)a0.w,
                      (__bf16)a1.x, (__bf16)a1.y, (__bf16)a1.z, (__bf16)a1.w };
        bf16x8 bf = { (__bf16)b0.x, (__bf16)b0.y, (__bf16)b0.z, (__bf16)b0.w,
                      (__bf16)b1.x, (__bf16)b1.y, (__bf16)b1.z, (__bf16)b1.w };
        acc = __builtin_amdgcn_mfma_f32_32x32x16_bf16(af, bf, acc, 0, 0, 0);
        a0 = na0; a1 = na1; b0 = nb0; b1 = nb1;
    }

    // epilogue: per-wave 32x32 transpose through LDS (stride 40 halfs so
    // 16-half rows are 16B-aligned for vector reads), hT store + fused edges.
    _Float16* tt = tts + wave * 1280;   // 32x40, disjoint per wave
#pragma unroll
    for (int reg = 0; reg < 16; ++reg) {
        int rowl = (reg & 3) + 8 * (reg >> 2) + 4 * half;   // i_local
        tt[rowl * 40 + l31] = (_Float16)acc[reg];           // [i][o]
    }
    // same-wave LDS write->read: no cross-wave barrier needed
    int orow = lane >> 1;
    int li = (lane & 1) * 16;
    half8 h0, h1;
#pragma unroll
    for (int t = 0; t < 8; ++t) h0[t] = tt[(li + t) * 40 + orow];
#pragma unroll
    for (int t = 0; t < 8; ++t) h1[t] = tt[(li + 8 + t) * 40 + orow];
    _Float16* op = hT + (long)(o0 + wc * 32 + orow) * NROW + i0 + wr * 32 + li;
    *reinterpret_cast<half8*>(op) = h0;
    *reinterpret_cast<half8*>(op + 8) = h1;

    // fused edges: row l31, d-slice [wc*32 + half*16, +16)
    half8 hv0 = *reinterpret_cast<const half8*>(tt + l31 * 40 + half * 16);
    half8 hv1 = *reinterpret_cast<const half8*>(tt + l31 * 40 + half * 16 + 8);
    const float* ap = a_src + head * ND + wc * 32 + half * 16;
    const float* dp = a_dst + head * ND + wc * 32 + half * 16;
    float4 as0 = *reinterpret_cast<const float4*>(ap);
    float4 as1 = *reinterpret_cast<const float4*>(ap + 4);
    float4 as2 = *reinterpret_cast<const float4*>(ap + 8);
    float4 as3 = *reinterpret_cast<const float4*>(ap + 12);
    float4 ad0 = *reinterpret_cast<const float4*>(dp);
    float4 ad1 = *reinterpret_cast<const float4*>(dp + 4);
    float4 ad2 = *reinterpret_cast<const float4*>(dp + 8);
    float4 ad3 = *reinterpret_cast<const float4*>(dp + 12);
    float ps = 0.f, pd = 0.f;
    ps += (float)hv0[0]*as0.x + (float)hv0[1]*as0.y + (float)hv0[2]*as0.z + (float)hv0[3]*as0.w;
    ps += (float)hv0[4]*as1.x + (float)hv0[5]*as1.y + (float)hv0[6]*as1.z + (float)hv0[7]*as1.w;
    ps += (float)hv1[0]*as2.x + (float)hv1[1]*as2.y + (float)hv1[2]*as2.z + (float)hv1[3]*as2.w;
    ps += (float)hv1[4]*as3.x + (float)hv1[5]*as3.y + (float)hv1[6]*as3.z + (float)hv1[7]*as3.w;
    pd += (float)hv0[0]*ad0.x + (float)hv0[1]*ad0.y + (float)hv0[2]*ad0.z + (float)hv0[3]*ad0.w;
    pd += (float)hv0[4]*ad1.x + (float)hv0[5]*ad1.y + (float)hv0[6]*ad1.z + (float)hv0[7]*ad1.w;
    pd += (float)hv1[0]*ad2.x + (float)hv1[1]*ad2.y + (float)hv1[2]*ad2.z + (float)hv1[3]*ad2.w;
    pd += (float)hv1[4]*ad3.x + (float)hv1[5]*ad3.y + (float)hv1[6]*ad3.z + (float)hv1[7]*ad3.w;
    ps += __shfl_xor(ps, 32, 64);   // combine d half-slices
    pd += __shfl_xor(pd, 32, 64);
    if (half == 0) { ered[0][wr][wc][l31] = ps; ered[1][wr][wc][l31] = pd; }
    __syncthreads();
    if (wc == 0) {
        float pst = ered[0][wr][0][l31] + ered[0][wr][1][l31];
        float pdt = ered[1][wr][0][l31] + ered[1][wr][1][l31];
        if (half == 0) {
            e_srcT[head * NROW + i0 + wr * 32 + l31] = pst;
            e_dstT[head * NROW + i0 + wr * 32 + l31] = pdt;
        }
        float mx = pdt;
#pragma unroll
        for (int off = 1; off < 32; off <<= 1) mx = fmaxf(mx, __shfl_xor(mx, off, 64));
        if (lane == 0) atomicMax(&maxkey[head], gat_enc_key(mx));
    }
}

// ---------------------------------------------------------------------------
// Stage 3: masked softmax-PV with 32x32x16 FP16 MFMA, packed-f16 p-compute.
// p-row factor A_i cancels between num and den in the final division, so the
// kernel computes the UNSCALED af = max(P_j, Q_j * R_i) * mask, with
// R = exp(-0.8u) unconditionally. Mask via 64-bit interleaved sign-spread:
// S64 has w8 even bits at 15,17,19,21 and odd bits at 31,33,35,37; then
// low32(S64 >> 2t) has bit15 = w8[2t], bit31 = w8[2t+1] for all t=0..3 and
// pk_ashr_i16(.,15) spreads both to 16-bit lane masks (3 ops/pair).
// den on the MFMA pipe via ones-B. Grid: 24 x 4 jc x 8 heads = 768 blocks.
// ---------------------------------------------------------------------------
__global__ __launch_bounds__(256) void gat_attn(const unsigned* __restrict__ bits,
                                                const float* __restrict__ e_srcT,
                                                const float* __restrict__ e_dstT,
                                                const unsigned* __restrict__ maxkey,
                                                const _Float16* __restrict__ hT,
                                                _Float16* __restrict__ num,
                                                float* __restrict__ den) {
    constexpr int JCHUNK = NROW / 4;         // 768
    constexpr int NC = JCHUNK / 64;          // 12 chunks of 64 j
    __shared__ unsigned lds_P[JCHUNK / 2];               // 1.5 KB (half2 pairs)
    __shared__ unsigned lds_Q[JCHUNK / 2];               // 1.5 KB
    __shared__ __align__(16) _Float16 hbuf[2][4096];     // 2 x 8 KB
    int b = blockIdx.x;
    int head = b & 7;
    int jc = (b >> 3) & 3;
    int i0 = ((b >> 3) >> 2) * 128;
    int jbase = jc * JCHUNK;
    int tid = threadIdx.x;
    int wave = tid >> 6;
    int lane = tid & 63;
    int half = lane >> 5;
    int l31 = lane & 31;

    float Mg = gat_dec_key(maxkey[head]);
    for (int p = tid; p < JCHUNK / 2; p += 256) {
        float t0 = e_dstT[head * NROW + jbase + 2 * p] - Mg;      // <= 0
        float t1 = e_dstT[head * NROW + jbase + 2 * p + 1] - Mg;
        half2v P = { (_Float16)__expf(t0), (_Float16)__expf(t1) };
        half2v Q = { (_Float16)__expf(0.2f * t0), (_Float16)__expf(0.2f * t1) };
        lds_P[p] = __builtin_bit_cast(unsigned, P);
        lds_Q[p] = __builtin_bit_cast(unsigned, Q);
    }

    int irow = i0 + wave * 32 + l31;
    float u = e_srcT[head * NROW + irow] + Mg;
    float Rf = fminf(__expf(-0.8f * u), 60000.f);
    _Float16 Rh = (_Float16)Rf;
    half2v R2 = { Rh, Rh };
    const half8 ones8 = { (_Float16)1.f, (_Float16)1.f, (_Float16)1.f, (_Float16)1.f,
                          (_Float16)1.f, (_Float16)1.f, (_Float16)1.f, (_Float16)1.f };
    const unsigned* brow = bits + irow * 96 + jc * (JCHUNK / 32);

    // staging: 512 slots of 16 B; slot s: js=s>>7, dh=(s>>6)&1, sl=s&63;
    // thread t stages slots t and t+256.
    int s0 = tid, s1 = tid + 256;
    const _Float16* gp0 = hT + (head * ND + ((s0 >> 6) & 1) * 32 + (s0 & 31)) * NROW
                             + jbase + (s0 >> 7) * 16 + ((s0 >> 5) & 1) * 8;
    const _Float16* gp1 = hT + (head * ND + ((s1 >> 6) & 1) * 32 + (s1 & 31)) * NROW
                             + jbase + (s1 >> 7) * 16 + ((s1 >> 5) & 1) * 8;
    *reinterpret_cast<half8*>(&hbuf[0][tid * 8])         = *reinterpret_cast<const half8*>(gp0);
    *reinterpret_cast<half8*>(&hbuf[0][(tid + 256) * 8]) = *reinterpret_cast<const half8*>(gp1);
    __syncthreads();

    f32x16 acc0 = {};
    f32x16 acc1 = {};
    f32x16 acc2 = {};
    uint2 wm = *reinterpret_cast<const uint2*>(brow);

    for (int k = 0; k < NC; ++k) {
        half8 st0, st1;
        uint2 wmn = wm;
        bool more = (k + 1 < NC);
        if (more) {
            st0 = *reinterpret_cast<const half8*>(gp0 + (k + 1) * 64);
            st1 = *reinterpret_cast<const half8*>(gp1 + (k + 1) * 64);
            wmn = *reinterpret_cast<const uint2*>(brow + (k + 1) * 2);
        }
        const _Float16* hb = &hbuf[k & 1][0];
#pragma unroll
        for (int js = 0; js < 4; ++js) {
            unsigned word = (js < 2) ? wm.x : wm.y;
            unsigned w8 = (word >> ((js & 1) * 16 + half * 8)) & 0xffu;
            unsigned long long S64 = ((unsigned long long)(w8 & 0x55u) << 15)
                                   | ((unsigned long long)(w8 & 0xAAu) << 30);
            uint4 Pv = *reinterpret_cast<const uint4*>(&lds_P[k * 32 + js * 8 + half * 4]);
            uint4 Qv = *reinterpret_cast<const uint4*>(&lds_Q[k * 32 + js * 8 + half * 4]);
            unsigned pr[4] = { Pv.x, Pv.y, Pv.z, Pv.w };
            unsigned qr[4] = { Qv.x, Qv.y, Qv.z, Qv.w };
            unsigned am[4];
#pragma unroll
            for (int t = 0; t < 4; ++t) {
                half2v qq = __builtin_bit_cast(half2v, qr[t]) * R2;            // pk_mul
                half2v mx = __builtin_elementwise_max(
                                __builtin_bit_cast(half2v, pr[t]), qq);        // pk_max
                unsigned Wt = (unsigned)(S64 >> (2 * t));
                s16x2 mks = __builtin_bit_cast(s16x2, Wt) >> 15;               // pk_ashr
                am[t] = __builtin_bit_cast(unsigned, mx)
                      & __builtin_bit_cast(unsigned, mks);
            }
            uint4 m4 = { am[0], am[1], am[2], am[3] };
            half8 af = __builtin_bit_cast(half8, m4);                          // free repack
            half8 v0 = *reinterpret_cast<const half8*>(hb + (js * 128 + lane) * 8);
            half8 v1 = *reinterpret_cast<const half8*>(hb + (js * 128 + 64 + lane) * 8);
            acc0 = __builtin_amdgcn_mfma_f32_32x32x16_f16(af, v0, acc0, 0, 0, 0);
            acc1 = __builtin_amdgcn_mfma_f32_32x32x16_f16(af, v1, acc1, 0, 0, 0);
            acc2 = __builtin_amdgcn_mfma_f32_32x32x16_f16(af, ones8, acc2, 0, 0, 0);
        }
        if (more) {
            *reinterpret_cast<half8*>(&hbuf[(k + 1) & 1][tid * 8])         = st0;
            *reinterpret_cast<half8*>(&hbuf[(k + 1) & 1][(tid + 256) * 8]) = st1;
        }
        wm = wmn;
        __syncthreads();
    }

    // epilogue: den from acc2 ones-column, num stores (A_i cancels -> no scale).
#pragma unroll
    for (int reg = 0; reg < 16; ++reg) {
        int rowl = (reg & 3) + 8 * (reg >> 2) + 4 * half;
        if (l31 == 0)
            den[(long)(jc * NROW + i0 + wave * 32 + rowl) * NH + head] = acc2[reg];
        long ob = (long)(jc * NROW + i0 + wave * 32 + rowl) * NF + head * ND + l31;
        num[ob]      = (_Float16)acc0[reg];
        num[ob + 32] = (_Float16)acc1[reg];
    }
}

// ---------------------------------------------------------------------------
// Stage 4: out[i,c..c+7] = sum_jc num[jc][i][c..] / sum_jc den[jc][i][c>>6]
// Vectorized: one thread = 8 consecutive c (half8 loads, float4 stores).
// Grid 768 x 256.
// ---------------------------------------------------------------------------
__global__ __launch_bounds__(256) void gat_final(const _Float16* __restrict__ num,
                                                 const float* __restrict__ den,
                                                 float* __restrict__ out) {
    int idx = (blockIdx.x * 256 + threadIdx.x) * 8;   // 0 .. NROW*NF step 8
    int i = idx >> 9;
    int c = idx & 511;
    int head = c >> 6;
    half8 n0 = *reinterpret_cast<const half8*>(num + (long)i * NF + c);
    half8 n1 = *reinterpret_cast<const half8*>(num + (long)(NROW + i) * NF + c);
    half8 n2 = *reinterpret_cast<const half8*>(num + (long)(2 * NROW + i) * NF + c);
    half8 n3 = *reinterpret_cast<const half8*>(num + (long)(3 * NROW + i) * NF + c);
    float ds = den[i * NH + head] + den[(NROW + i) * NH + head]
             + den[(2 * NROW + i) * NH + head] + den[(3 * NROW + i) * NH + head];
    float inv = 1.0f / fmaxf(ds, 1e-30f);
    float r0 = ((float)n0[0] + (float)n1[0] + (float)n2[0] + (float)n3[0]) * inv;
    float r1 = ((float)n0[1] + (float)n1[1] + (float)n2[1] + (float)n3[1]) * inv;
    float r2 = ((float)n0[2] + (float)n1[2] + (float)n2[2] + (float)n3[2]) * inv;
    float r3 = ((float)n0[3] + (float)n1[3] + (float)n2[3] + (float)n3[3]) * inv;
    float r4 = ((float)n0[4] + (float)n1[4] + (float)n2[4] + (float)n3[4]) * inv;
    float r5 = ((float)n0[5] + (float)n1[5] + (float)n2[5] + (float)n3[5]) * inv;
    float r6 = ((float)n0[6] + (float)n1[6] + (float)n2[6] + (float)n3[6]) * inv;
    float r7 = ((float)n0[7] + (float)n1[7] + (float)n2[7] + (float)n3[7]) * inv;
    float4 o0 = { r0, r1, r2, r3 };
    float4 o1 = { r4, r5, r6, r7 };
    *reinterpret_cast<float4*>(out + idx)     = o0;
    *reinterpret_cast<float4*>(out + idx + 4) = o1;
}

// ---------------------------------------------------------------------------
extern "C" void kernel_launch(void* const* d_in, const int* in_sizes, int n_in,
                              void* d_out, int out_size, void* d_ws, size_t ws_size,
                              hipStream_t stream) {
    const float* x_raw  = (const float*)d_in[0];
    const int*   adj    = (const int*)d_in[1];
    const float* W_raw  = (const float*)d_in[2];
    const float* as_raw = (const float*)d_in[3];
    const float* ad_raw = (const float*)d_in[4];
    float* out = (float*)d_out;

    char* ws = (char*)d_ws;
    _Float16* hT     = (_Float16*)(ws);                  // 3,145,728 B
    float*    e_srcT = (float*)(ws + 3145728);           //    98,304 B
    float*    e_dstT = (float*)(ws + 3244032);           //    98,304 B
    unsigned* maxkey = (unsigned*)(ws + 3342336);        //        64 B
    unsigned* bits   = (unsigned*)(ws + 3342400);        // 1,179,648 B
    _Float16* num    = (_Float16*)(ws + 8192064);        // 12,582,912 B (f16)
    float*    den    = (float*)(ws + 20774976);          //   393,216 B
    // total 21,168,192 B (<= previously-verified capacity)

    hipMemsetAsync(maxkey, 0, 64, stream);
    gat_gemm_bp<<<GEMM_BLOCKS + BP_BLOCKS, 256, 0, stream>>>(x_raw, W_raw, hT, adj,
                                                             bits, as_raw, ad_raw,
                                                             e_srcT, e_dstT, maxkey);
    gat_attn<<<24 * 4 * 8, 256, 0, stream>>>(bits, e_srcT, e_dstT, maxkey, hT, num, den);
    gat_final<<<NROW * NF / 2048, 256, 0, stream>>>(num, den, out);
}

// Round 9
// 140.604 us; speedup vs baseline: 1.0379x; 1.0379x over previous
//
#include <hip/hip_runtime.h>
#include <hip/hip_bf16.h>

typedef __bf16 bf16x8 __attribute__((ext_vector_type(8)));
typedef _Float16 half8 __attribute__((ext_vector_type(8)));
typedef _Float16 half2v __attribute__((ext_vector_type(2)));
typedef short s16x2 __attribute__((ext_vector_type(2)));
typedef float f32x4 __attribute__((ext_vector_type(4)));
typedef float f32x16 __attribute__((ext_vector_type(16)));

#define NROW 3072
#define NF 512            // IN_F == H*D == 512
#define NH 8
#define ND 64

// Order-preserving float<->uint key for atomicMax over signed floats.
// key 0 is below every encoded finite float -> memset(0) is a valid init.
__device__ __forceinline__ unsigned gat_enc_key(float f) {
    unsigned u = __float_as_uint(f);
    return (f < 0.f) ? ~u : (u | 0x80000000u);
}
__device__ __forceinline__ float gat_dec_key(unsigned k) {
    unsigned u = (k & 0x80000000u) ? (k ^ 0x80000000u) : ~k;
    return __uint_as_float(u);
}

__device__ __forceinline__ bf16x8 gat_ld_cvt8(const float* p) {
    float4 f0 = *reinterpret_cast<const float4*>(p);
    float4 f1 = *reinterpret_cast<const float4*>(p + 4);
    bf16x8 o = { (__bf16)f0.x, (__bf16)f0.y, (__bf16)f0.z, (__bf16)f0.w,
                 (__bf16)f1.x, (__bf16)f1.y, (__bf16)f1.z, (__bf16)f1.w };
    return o;
}

// ---------------------------------------------------------------------------
// Stage 0: bitpack (adj>0 || j==i) -> bits[3072][48] u64, SPLIT OUT for
// dispatch-level visibility. One wave per row. Coalesced: lane l reads
// adj[row][seg*64+l] (4 B/lane consecutive, 4 lines/instr) — NOT the R6
// 128-B-lane-strided int4 pattern (64 lines/instr, the pathology R8 exposed
// on the gemm). All 48 seg loads are hoisted into named registers via full
// unroll (48 loads in flight/wave), then 48 ballots + lane-0 stores.
// 768 blocks x 4 waves. Floor: 37.7 MB cold HBM ~ 6 us.
// ---------------------------------------------------------------------------
__global__ __launch_bounds__(256) void gat_bitpack(const int* __restrict__ adj,
                                                   unsigned long long* __restrict__ bits64) {
    int wave = threadIdx.x >> 6;
    int lane = threadIdx.x & 63;
    int row = blockIdx.x * 4 + wave;
    const int* p = adj + (long)row * NROW + lane;
    int v[48];
#pragma unroll
    for (int s = 0; s < 48; ++s) v[s] = p[s * 64];
    unsigned long long diag = 1ull << (row & 63);
    int dseg = row >> 6;
#pragma unroll
    for (int s = 0; s < 48; ++s) {
        unsigned long long bal = __ballot(v[s] > 0);
        if (s == dseg) bal |= diag;                  // wave-uniform
        if (lane == 0) bits64[(long)row * 48 + s] = bal;
    }
}

// ---------------------------------------------------------------------------
// Stage 1: h = x @ W^T, 64x64 block tiles (4 waves x 32x32 mfma_32x32x16),
// BK=32, padded stride-40-half LDS (21.5 KB), depth-2 register staging
// (R7-verified structure, restored after R8's no-LDS regression).
// Epilogue: per-wave LDS transpose -> hT store + fused e_src/e_dst +
// per-head atomicMax. 384 blocks.
// ---------------------------------------------------------------------------
__global__ __launch_bounds__(256) void gat_gemm(const float* __restrict__ x,
                                                const float* __restrict__ W,
                                                _Float16* __restrict__ hT,
                                                const float* __restrict__ a_src,
                                                const float* __restrict__ a_dst,
                                                float* __restrict__ e_srcT,
                                                float* __restrict__ e_dstT,
                                                unsigned* __restrict__ maxkey) {
    __shared__ __align__(16) _Float16 smem[10240];  // A: [0,5120) halfs, B: [5120,10240)
    __shared__ float ered[2][2][2][32];             // [src/dst][wr][wc][row]

    int b = blockIdx.x;                 // 48 i-panels x 8 o-groups (= heads)
    int i0 = (b >> 3) * 64;
    int o0 = (b & 7) * 64;
    int head = b & 7;
    int tid = threadIdx.x;
    int wave = tid >> 6;
    int lane = tid & 63;
    int half = lane >> 5;
    int l31 = lane & 31;
    int wr = wave >> 1;                 // i sub-tile (0/1)
    int wc = wave & 1;                  // o sub-tile (0/1)

    __bf16* sA = reinterpret_cast<__bf16*>(smem);          // 2 bufs x 64 rows x 40 halfs
    __bf16* sB = reinterpret_cast<__bf16*>(smem) + 5120;

    // staging: 256 slots of 16 B per operand per chunk; thread t owns slot t.
    int r = tid >> 2;
    int pp = tid & 3;
    const float* gA = x + (i0 + r) * NF + pp * 8;
    const float* gB = W + (o0 + r) * NF + pp * 8;
    int dslot = r * 40 + pp * 8;

    // depth-2 pipeline prologue: chunk0 -> regs -> LDS buf0; issue chunk1.
    bf16x8 pA0, pB0, pA1, pB1;
    pA0 = gat_ld_cvt8(gA);
    pB0 = gat_ld_cvt8(gB);
    *reinterpret_cast<bf16x8*>(sA + dslot) = pA0;
    *reinterpret_cast<bf16x8*>(sB + dslot) = pB0;
    pA1 = gat_ld_cvt8(gA + 32);
    pB1 = gat_ld_cvt8(gB + 32);
    __syncthreads();

    f32x16 acc = {};
    int arow = (wr * 32 + l31) * 40;
    int brow = (wc * 32 + l31) * 40;

#pragma unroll
    for (int cc = 0; cc < 8; ++cc) {
        // ---- even chunk c0 = 2*cc: compute from buf0 ----
        int c0 = cc * 2;
        if (c0 + 2 < 16) {
            pA0 = gat_ld_cvt8(gA + (c0 + 2) * 32);
            pB0 = gat_ld_cvt8(gB + (c0 + 2) * 32);
        }
        {
            const __bf16* pa = sA;
            const __bf16* pb = sB;
#pragma unroll
            for (int ks = 0; ks < 2; ++ks) {
                int q = (((ks << 1) | half)) << 3;
                bf16x8 a = *reinterpret_cast<const bf16x8*>(pa + arow + q);
                bf16x8 bb = *reinterpret_cast<const bf16x8*>(pb + brow + q);
                acc = __builtin_amdgcn_mfma_f32_32x32x16_bf16(a, bb, acc, 0, 0, 0);
            }
        }
        *reinterpret_cast<bf16x8*>(sA + 2560 + dslot) = pA1;
        *reinterpret_cast<bf16x8*>(sB + 2560 + dslot) = pB1;
        __syncthreads();

        // ---- odd chunk c1 = 2*cc+1: compute from buf1 ----
        int c1 = c0 + 1;
        if (c1 + 2 < 16) {
            pA1 = gat_ld_cvt8(gA + (c1 + 2) * 32);
            pB1 = gat_ld_cvt8(gB + (c1 + 2) * 32);
        }
        {
            const __bf16* pa = sA + 2560;
            const __bf16* pb = sB + 2560;
#pragma unroll
            for (int ks = 0; ks < 2; ++ks) {
                int q = (((ks << 1) | half)) << 3;
                bf16x8 a = *reinterpret_cast<const bf16x8*>(pa + arow + q);
                bf16x8 bb = *reinterpret_cast<const bf16x8*>(pb + brow + q);
                acc = __builtin_amdgcn_mfma_f32_32x32x16_bf16(a, bb, acc, 0, 0, 0);
            }
        }
        if (c1 + 1 < 16) {
            *reinterpret_cast<bf16x8*>(sA + dslot) = pA0;
            *reinterpret_cast<bf16x8*>(sB + dslot) = pB0;
        }
        __syncthreads();
    }

    // epilogue: per-wave 32x32 transpose through LDS (stride 40 halfs so
    // 16-half rows are 16B-aligned for vector reads), hT store + fused edges.
    _Float16* tt = smem + wave * 1280;   // 32x40, disjoint per wave
#pragma unroll
    for (int reg = 0; reg < 16; ++reg) {
        int rowl = (reg & 3) + 8 * (reg >> 2) + 4 * half;   // i_local
        tt[rowl * 40 + l31] = (_Float16)acc[reg];           // [i][o]
    }
    // same-wave LDS write->read: no cross-wave barrier needed
    int orow = lane >> 1;
    int li = (lane & 1) * 16;
    half8 h0, h1;
#pragma unroll
    for (int t = 0; t < 8; ++t) h0[t] = tt[(li + t) * 40 + orow];
#pragma unroll
    for (int t = 0; t < 8; ++t) h1[t] = tt[(li + 8 + t) * 40 + orow];
    _Float16* op = hT + (long)(o0 + wc * 32 + orow) * NROW + i0 + wr * 32 + li;
    *reinterpret_cast<half8*>(op) = h0;
    *reinterpret_cast<half8*>(op + 8) = h1;

    // fused edges: row l31, d-slice [wc*32 + half*16, +16)
    half8 hv0 = *reinterpret_cast<const half8*>(tt + l31 * 40 + half * 16);
    half8 hv1 = *reinterpret_cast<const half8*>(tt + l31 * 40 + half * 16 + 8);
    const float* ap = a_src + head * ND + wc * 32 + half * 16;
    const float* dp = a_dst + head * ND + wc * 32 + half * 16;
    float4 as0 = *reinterpret_cast<const float4*>(ap);
    float4 as1 = *reinterpret_cast<const float4*>(ap + 4);
    float4 as2 = *reinterpret_cast<const float4*>(ap + 8);
    float4 as3 = *reinterpret_cast<const float4*>(ap + 12);
    float4 ad0 = *reinterpret_cast<const float4*>(dp);
    float4 ad1 = *reinterpret_cast<const float4*>(dp + 4);
    float4 ad2 = *reinterpret_cast<const float4*>(dp + 8);
    float4 ad3 = *reinterpret_cast<const float4*>(dp + 12);
    float ps = 0.f, pd = 0.f;
    ps += (float)hv0[0]*as0.x + (float)hv0[1]*as0.y + (float)hv0[2]*as0.z + (float)hv0[3]*as0.w;
    ps += (float)hv0[4]*as1.x + (float)hv0[5]*as1.y + (float)hv0[6]*as1.z + (float)hv0[7]*as1.w;
    ps += (float)hv1[0]*as2.x + (float)hv1[1]*as2.y + (float)hv1[2]*as2.z + (float)hv1[3]*as2.w;
    ps += (float)hv1[4]*as3.x + (float)hv1[5]*as3.y + (float)hv1[6]*as3.z + (float)hv1[7]*as3.w;
    pd += (float)hv0[0]*ad0.x + (float)hv0[1]*ad0.y + (float)hv0[2]*ad0.z + (float)hv0[3]*ad0.w;
    pd += (float)hv0[4]*ad1.x + (float)hv0[5]*ad1.y + (float)hv0[6]*ad1.z + (float)hv0[7]*ad1.w;
    pd += (float)hv1[0]*ad2.x + (float)hv1[1]*ad2.y + (float)hv1[2]*ad2.z + (float)hv1[3]*ad2.w;
    pd += (float)hv1[4]*ad3.x + (float)hv1[5]*ad3.y + (float)hv1[6]*ad3.z + (float)hv1[7]*ad3.w;
    ps += __shfl_xor(ps, 32, 64);   // combine d half-slices
    pd += __shfl_xor(pd, 32, 64);
    if (half == 0) { ered[0][wr][wc][l31] = ps; ered[1][wr][wc][l31] = pd; }
    __syncthreads();
    if (wc == 0) {
        float pst = ered[0][wr][0][l31] + ered[0][wr][1][l31];
        float pdt = ered[1][wr][0][l31] + ered[1][wr][1][l31];
        if (half == 0) {
            e_srcT[head * NROW + i0 + wr * 32 + l31] = pst;
            e_dstT[head * NROW + i0 + wr * 32 + l31] = pdt;
        }
        float mx = pdt;
#pragma unroll
        for (int off = 1; off < 32; off <<= 1) mx = fmaxf(mx, __shfl_xor(mx, off, 64));
        if (lane == 0) atomicMax(&maxkey[head], gat_enc_key(mx));
    }
}

// ---------------------------------------------------------------------------
// Stage 3: masked softmax-PV with 32x32x16 FP16 MFMA, packed-f16 p-compute.
// p-row factor A_i cancels between num and den in the final division, so the
// kernel computes the UNSCALED af = max(P_j, Q_j * R_i) * mask, with
// R = exp(-0.8u) unconditionally. Mask via 64-bit interleaved sign-spread:
// S64 has w8 even bits at 15,17,19,21 and odd bits at 31,33,35,37; then
// low32(S64 >> 2t) has bit15 = w8[2t], bit31 = w8[2t+1] for all t=0..3 and
// pk_ashr_i16(.,15) spreads both to 16-bit lane masks (3 ops/pair).
// den on the MFMA pipe via ones-B. Grid: 24 x 4 jc x 8 heads = 768 blocks.
// ---------------------------------------------------------------------------
__global__ __launch_bounds__(256) void gat_attn(const unsigned* __restrict__ bits,
                                                const float* __restrict__ e_srcT,
                                                const float* __restrict__ e_dstT,
                                                const unsigned* __restrict__ maxkey,
                                                const _Float16* __restrict__ hT,
                                                _Float16* __restrict__ num,
                                                float* __restrict__ den) {
    constexpr int JCHUNK = NROW / 4;         // 768
    constexpr int NC = JCHUNK / 64;          // 12 chunks of 64 j
    __shared__ unsigned lds_P[JCHUNK / 2];               // 1.5 KB (half2 pairs)
    __shared__ unsigned lds_Q[JCHUNK / 2];               // 1.5 KB
    __shared__ __align__(16) _Float16 hbuf[2][4096];     // 2 x 8 KB
    int b = blockIdx.x;
    int head = b & 7;
    int jc = (b >> 3) & 3;
    int i0 = ((b >> 3) >> 2) * 128;
    int jbase = jc * JCHUNK;
    int tid = threadIdx.x;
    int wave = tid >> 6;
    int lane = tid & 63;
    int half = lane >> 5;
    int l31 = lane & 31;

    float Mg = gat_dec_key(maxkey[head]);
    for (int p = tid; p < JCHUNK / 2; p += 256) {
        float t0 = e_dstT[head * NROW + jbase + 2 * p] - Mg;      // <= 0
        float t1 = e_dstT[head * NROW + jbase + 2 * p + 1] - Mg;
        half2v P = { (_Float16)__expf(t0), (_Float16)__expf(t1) };
        half2v Q = { (_Float16)__expf(0.2f * t0), (_Float16)__expf(0.2f * t1) };
        lds_P[p] = __builtin_bit_cast(unsigned, P);
        lds_Q[p] = __builtin_bit_cast(unsigned, Q);
    }

    int irow = i0 + wave * 32 + l31;
    float u = e_srcT[head * NROW + irow] + Mg;
    float Rf = fminf(__expf(-0.8f * u), 60000.f);
    _Float16 Rh = (_Float16)Rf;
    half2v R2 = { Rh, Rh };
    const half8 ones8 = { (_Float16)1.f, (_Float16)1.f, (_Float16)1.f, (_Float16)1.f,
                          (_Float16)1.f, (_Float16)1.f, (_Float16)1.f, (_Float16)1.f };
    const unsigned* brow = bits + irow * 96 + jc * (JCHUNK / 32);

    // staging: 512 slots of 16 B; slot s: js=s>>7, dh=(s>>6)&1, sl=s&63;
    // thread t stages slots t and t+256.
    int s0 = tid, s1 = tid + 256;
    const _Float16* gp0 = hT + (head * ND + ((s0 >> 6) & 1) * 32 + (s0 & 31)) * NROW
                             + jbase + (s0 >> 7) * 16 + ((s0 >> 5) & 1) * 8;
    const _Float16* gp1 = hT + (head * ND + ((s1 >> 6) & 1) * 32 + (s1 & 31)) * NROW
                             + jbase + (s1 >> 7) * 16 + ((s1 >> 5) & 1) * 8;
    *reinterpret_cast<half8*>(&hbuf[0][tid * 8])         = *reinterpret_cast<const half8*>(gp0);
    *reinterpret_cast<half8*>(&hbuf[0][(tid + 256) * 8]) = *reinterpret_cast<const half8*>(gp1);
    __syncthreads();

    f32x16 acc0 = {};
    f32x16 acc1 = {};
    f32x16 acc2 = {};
    uint2 wm = *reinterpret_cast<const uint2*>(brow);

    for (int k = 0; k < NC; ++k) {
        half8 st0, st1;
        uint2 wmn = wm;
        bool more = (k + 1 < NC);
        if (more) {
            st0 = *reinterpret_cast<const half8*>(gp0 + (k + 1) * 64);
            st1 = *reinterpret_cast<const half8*>(gp1 + (k + 1) * 64);
            wmn = *reinterpret_cast<const uint2*>(brow + (k + 1) * 2);
        }
        const _Float16* hb = &hbuf[k & 1][0];
#pragma unroll
        for (int js = 0; js < 4; ++js) {
            unsigned word = (js < 2) ? wm.x : wm.y;
            unsigned w8 = (word >> ((js & 1) * 16 + half * 8)) & 0xffu;
            unsigned long long S64 = ((unsigned long long)(w8 & 0x55u) << 15)
                                   | ((unsigned long long)(w8 & 0xAAu) << 30);
            uint4 Pv = *reinterpret_cast<const uint4*>(&lds_P[k * 32 + js * 8 + half * 4]);
            uint4 Qv = *reinterpret_cast<const uint4*>(&lds_Q[k * 32 + js * 8 + half * 4]);
            unsigned pr[4] = { Pv.x, Pv.y, Pv.z, Pv.w };
            unsigned qr[4] = { Qv.x, Qv.y, Qv.z, Qv.w };
            unsigned am[4];
#pragma unroll
            for (int t = 0; t < 4; ++t) {
                half2v qq = __builtin_bit_cast(half2v, qr[t]) * R2;            // pk_mul
                half2v mx = __builtin_elementwise_max(
                                __builtin_bit_cast(half2v, pr[t]), qq);        // pk_max
                unsigned Wt = (unsigned)(S64 >> (2 * t));
                s16x2 mks = __builtin_bit_cast(s16x2, Wt) >> 15;               // pk_ashr
                am[t] = __builtin_bit_cast(unsigned, mx)
                      & __builtin_bit_cast(unsigned, mks);
            }
            uint4 m4 = { am[0], am[1], am[2], am[3] };
            half8 af = __builtin_bit_cast(half8, m4);                          // free repack
            half8 v0 = *reinterpret_cast<const half8*>(hb + (js * 128 + lane) * 8);
            half8 v1 = *reinterpret_cast<const half8*>(hb + (js * 128 + 64 + lane) * 8);
            acc0 = __builtin_amdgcn_mfma_f32_32x32x16_f16(af, v0, acc0, 0, 0, 0);
            acc1 = __builtin_amdgcn_mfma_f32_32x32x16_f16(af, v1, acc1, 0, 0, 0);
            acc2 = __builtin_amdgcn_mfma_f32_32x32x16_f16(af, ones8, acc2, 0, 0, 0);
        }
        if (more) {
            *reinterpret_cast<half8*>(&hbuf[(k + 1) & 1][tid * 8])         = st0;
            *reinterpret_cast<half8*>(&hbuf[(k + 1) & 1][(tid + 256) * 8]) = st1;
        }
        wm = wmn;
        __syncthreads();
    }

    // epilogue: den from acc2 ones-column, num stores (A_i cancels -> no scale).
#pragma unroll
    for (int reg = 0; reg < 16; ++reg) {
        int rowl = (reg & 3) + 8 * (reg >> 2) + 4 * half;
        if (l31 == 0)
            den[(long)(jc * NROW + i0 + wave * 32 + rowl) * NH + head] = acc2[reg];
        long ob = (long)(jc * NROW + i0 + wave * 32 + rowl) * NF + head * ND + l31;
        num[ob]      = (_Float16)acc0[reg];
        num[ob + 32] = (_Float16)acc1[reg];
    }
}

// ---------------------------------------------------------------------------
// Stage 4: out[i,c..c+7] = sum_jc num[jc][i][c..] / sum_jc den[jc][i][c>>6]
// Vectorized: one thread = 8 consecutive c (half8 loads, float4 stores).
// Grid 768 x 256.
// ---------------------------------------------------------------------------
__global__ __launch_bounds__(256) void gat_final(const _Float16* __restrict__ num,
                                                 const float* __restrict__ den,
                                                 float* __restrict__ out) {
    int idx = (blockIdx.x * 256 + threadIdx.x) * 8;   // 0 .. NROW*NF step 8
    int i = idx >> 9;
    int c = idx & 511;
    int head = c >> 6;
    half8 n0 = *reinterpret_cast<const half8*>(num + (long)i * NF + c);
    half8 n1 = *reinterpret_cast<const half8*>(num + (long)(NROW + i) * NF + c);
    half8 n2 = *reinterpret_cast<const half8*>(num + (long)(2 * NROW + i) * NF + c);
    half8 n3 = *reinterpret_cast<const half8*>(num + (long)(3 * NROW + i) * NF + c);
    float ds = den[i * NH + head] + den[(NROW + i) * NH + head]
             + den[(2 * NROW + i) * NH + head] + den[(3 * NROW + i) * NH + head];
    float inv = 1.0f / fmaxf(ds, 1e-30f);
    float r0 = ((float)n0[0] + (float)n1[0] + (float)n2[0] + (float)n3[0]) * inv;
    float r1 = ((float)n0[1] + (float)n1[1] + (float)n2[1] + (float)n3[1]) * inv;
    float r2 = ((float)n0[2] + (float)n1[2] + (float)n2[2] + (float)n3[2]) * inv;
    float r3 = ((float)n0[3] + (float)n1[3] + (float)n2[3] + (float)n3[3]) * inv;
    float r4 = ((float)n0[4] + (float)n1[4] + (float)n2[4] + (float)n3[4]) * inv;
    float r5 = ((float)n0[5] + (float)n1[5] + (float)n2[5] + (float)n3[5]) * inv;
    float r6 = ((float)n0[6] + (float)n1[6] + (float)n2[6] + (float)n3[6]) * inv;
    float r7 = ((float)n0[7] + (float)n1[7] + (float)n2[7] + (float)n3[7]) * inv;
    float4 o0 = { r0, r1, r2, r3 };
    float4 o1 = { r4, r5, r6, r7 };
    *reinterpret_cast<float4*>(out + idx)     = o0;
    *reinterpret_cast<float4*>(out + idx + 4) = o1;
}

// ---------------------------------------------------------------------------
extern "C" void kernel_launch(void* const* d_in, const int* in_sizes, int n_in,
                              void* d_out, int out_size, void* d_ws, size_t ws_size,
                              hipStream_t stream) {
    const float* x_raw  = (const float*)d_in[0];
    const int*   adj    = (const int*)d_in[1];
    const float* W_raw  = (const float*)d_in[2];
    const float* as_raw = (const float*)d_in[3];
    const float* ad_raw = (const float*)d_in[4];
    float* out = (float*)d_out;

    char* ws = (char*)d_ws;
    _Float16* hT     = (_Float16*)(ws);                  // 3,145,728 B
    float*    e_srcT = (float*)(ws + 3145728);           //    98,304 B
    float*    e_dstT = (float*)(ws + 3244032);           //    98,304 B
    unsigned* maxkey = (unsigned*)(ws + 3342336);        //        64 B
    unsigned* bits   = (unsigned*)(ws + 3342400);        // 1,179,648 B
    _Float16* num    = (_Float16*)(ws + 8192064);        // 12,582,912 B (f16)
    float*    den    = (float*)(ws + 20774976);          //   393,216 B
    // total 21,168,192 B (<= previously-verified capacity)

    hipMemsetAsync(maxkey, 0, 64, stream);
    gat_bitpack<<<NROW / 4, 256, 0, stream>>>(adj, (unsigned long long*)bits);
    gat_gemm<<<384, 256, 0, stream>>>(x_raw, W_raw, hT, as_raw, ad_raw,
                                      e_srcT, e_dstT, maxkey);
    gat_attn<<<24 * 4 * 8, 256, 0, stream>>>(bits, e_srcT, e_dstT, maxkey, hT, num, den);
    gat_final<<<NROW * NF / 2048, 256, 0, stream>>>(num, den, out);
}

// Round 10
// 134.068 us; speedup vs baseline: 1.0885x; 1.0488x over previous
//
#include <hip/hip_runtime.h>
#include <hip/hip_bf16.h>

typedef __bf16 bf16x8 __attribute__((ext_vector_type(8)));
typedef _Float16 half8 __attribute__((ext_vector_type(8)));
typedef _Float16 half2v __attribute__((ext_vector_type(2)));
typedef short s16x2 __attribute__((ext_vector_type(2)));
typedef float f32x4 __attribute__((ext_vector_type(4)));
typedef float f32x16 __attribute__((ext_vector_type(16)));

#define NROW 3072
#define NF 512            // IN_F == H*D == 512
#define NH 8
#define ND 64
#define BP_BLOCKS 768     // bitpack: 1 wave per row, 4 rows per block
#define GEMM_BLOCKS 384

// Order-preserving float<->uint key for atomicMax over signed floats.
// key 0 is below every encoded finite float -> memset(0) is a valid init.
__device__ __forceinline__ unsigned gat_enc_key(float f) {
    unsigned u = __float_as_uint(f);
    return (f < 0.f) ? ~u : (u | 0x80000000u);
}
__device__ __forceinline__ float gat_dec_key(unsigned k) {
    unsigned u = (k & 0x80000000u) ? (k ^ 0x80000000u) : ~k;
    return __uint_as_float(u);
}

__device__ __forceinline__ bf16x8 gat_ld_cvt8(const float* p) {
    float4 f0 = *reinterpret_cast<const float4*>(p);
    float4 f1 = *reinterpret_cast<const float4*>(p + 4);
    bf16x8 o = { (__bf16)f0.x, (__bf16)f0.y, (__bf16)f0.z, (__bf16)f0.w,
                 (__bf16)f1.x, (__bf16)f1.y, (__bf16)f1.z, (__bf16)f1.w };
    return o;
}

// ---------------------------------------------------------------------------
// Stage 1 (fused, R7 structure + R9 bitpack): blocks 0..767: coalesced
// ballot bitpack (adj>0 || j==i) — one wave per row, lane l reads
// adj[row][seg*64+l] (4 B/lane coalesced, 4 lines/instr), 48 loads hoisted
// into named regs (all in flight), then 48 ballots + lane-0 u64 stores.
// Blocks 768..1151: h = x @ W^T, 64x64 tiles (4 waves x 32x32
// mfma_32x32x16), BK=32, padded stride-40-half LDS (21.5 KB -> 7 blocks/CU,
// all 1152 blocks co-resident so HBM-bound bitpack overlaps L2-bound gemm).
// Gemm epilogue: per-wave LDS transpose -> hT + fused e_src/e_dst +
// per-head atomicMax.
// ---------------------------------------------------------------------------
__global__ __launch_bounds__(256) void gat_gemm_bp(const float* __restrict__ x,
                                                   const float* __restrict__ W,
                                                   _Float16* __restrict__ hT,
                                                   const int* __restrict__ adj,
                                                   unsigned long long* __restrict__ bits64,
                                                   const float* __restrict__ a_src,
                                                   const float* __restrict__ a_dst,
                                                   float* __restrict__ e_srcT,
                                                   float* __restrict__ e_dstT,
                                                   unsigned* __restrict__ maxkey) {
    __shared__ __align__(16) _Float16 smem[10240];  // A: [0,5120) halfs, B: [5120,10240)
    __shared__ float ered[2][2][2][32];             // [src/dst][wr][wc][row]

    int tid = threadIdx.x;
    int wave = tid >> 6;
    int lane = tid & 63;

    if (blockIdx.x < BP_BLOCKS) {
        // ---- bitpack path ----
        int row = blockIdx.x * 4 + wave;
        const int* p = adj + (long)row * NROW + lane;
        int v[48];
#pragma unroll
        for (int s = 0; s < 48; ++s) v[s] = p[s * 64];
        unsigned long long diag = 1ull << (row & 63);
        int dseg = row >> 6;
#pragma unroll
        for (int s = 0; s < 48; ++s) {
            unsigned long long bal = __ballot(v[s] > 0);
            if (s == dseg) bal |= diag;              // wave-uniform
            if (lane == 0) bits64[(long)row * 48 + s] = bal;
        }
        return;
    }

    // ---- gemm path ----
    int b = blockIdx.x - BP_BLOCKS;     // 48 i-panels x 8 o-groups (= heads)
    int i0 = (b >> 3) * 64;
    int o0 = (b & 7) * 64;
    int head = b & 7;
    int half = lane >> 5;
    int l31 = lane & 31;
    int wr = wave >> 1;                 // i sub-tile (0/1)
    int wc = wave & 1;                  // o sub-tile (0/1)

    __bf16* sA = reinterpret_cast<__bf16*>(smem);          // 2 bufs x 64 rows x 40 halfs
    __bf16* sB = reinterpret_cast<__bf16*>(smem) + 5120;

    // staging: 256 slots of 16 B per operand per chunk; thread t owns slot t.
    int r = tid >> 2;
    int pp = tid & 3;
    const float* gA = x + (i0 + r) * NF + pp * 8;
    const float* gB = W + (o0 + r) * NF + pp * 8;
    int dslot = r * 40 + pp * 8;

    // depth-2 pipeline prologue: chunk0 -> regs -> LDS buf0; issue chunk1.
    bf16x8 pA0, pB0, pA1, pB1;
    pA0 = gat_ld_cvt8(gA);
    pB0 = gat_ld_cvt8(gB);
    *reinterpret_cast<bf16x8*>(sA + dslot) = pA0;
    *reinterpret_cast<bf16x8*>(sB + dslot) = pB0;
    pA1 = gat_ld_cvt8(gA + 32);
    pB1 = gat_ld_cvt8(gB + 32);
    __syncthreads();

    f32x16 acc = {};
    int arow = (wr * 32 + l31) * 40;
    int brow = (wc * 32 + l31) * 40;

#pragma unroll
    for (int cc = 0; cc < 8; ++cc) {
        // ---- even chunk c0 = 2*cc: compute from buf0 ----
        int c0 = cc * 2;
        if (c0 + 2 < 16) {
            pA0 = gat_ld_cvt8(gA + (c0 + 2) * 32);
            pB0 = gat_ld_cvt8(gB + (c0 + 2) * 32);
        }
        {
            const __bf16* pa = sA;
            const __bf16* pb = sB;
#pragma unroll
            for (int ks = 0; ks < 2; ++ks) {
                int q = (((ks << 1) | half)) << 3;
                bf16x8 a = *reinterpret_cast<const bf16x8*>(pa + arow + q);
                bf16x8 bb = *reinterpret_cast<const bf16x8*>(pb + brow + q);
                acc = __builtin_amdgcn_mfma_f32_32x32x16_bf16(a, bb, acc, 0, 0, 0);
            }
        }
        *reinterpret_cast<bf16x8*>(sA + 2560 + dslot) = pA1;
        *reinterpret_cast<bf16x8*>(sB + 2560 + dslot) = pB1;
        __syncthreads();

        // ---- odd chunk c1 = 2*cc+1: compute from buf1 ----
        int c1 = c0 + 1;
        if (c1 + 2 < 16) {
            pA1 = gat_ld_cvt8(gA + (c1 + 2) * 32);
            pB1 = gat_ld_cvt8(gB + (c1 + 2) * 32);
        }
        {
            const __bf16* pa = sA + 2560;
            const __bf16* pb = sB + 2560;
#pragma unroll
            for (int ks = 0; ks < 2; ++ks) {
                int q = (((ks << 1) | half)) << 3;
                bf16x8 a = *reinterpret_cast<const bf16x8*>(pa + arow + q);
                bf16x8 bb = *reinterpret_cast<const bf16x8*>(pb + brow + q);
                acc = __builtin_amdgcn_mfma_f32_32x32x16_bf16(a, bb, acc, 0, 0, 0);
            }
        }
        if (c1 + 1 < 16) {
            *reinterpret_cast<bf16x8*>(sA + dslot) = pA0;
            *reinterpret_cast<bf16x8*>(sB + dslot) = pB0;
        }
        __syncthreads();
    }

    // epilogue: per-wave 32x32 transpose through LDS (stride 40 halfs so
    // 16-half rows are 16B-aligned for vector reads), hT store + fused edges.
    _Float16* tt = smem + wave * 1280;   // 32x40, disjoint per wave
#pragma unroll
    for (int reg = 0; reg < 16; ++reg) {
        int rowl = (reg & 3) + 8 * (reg >> 2) + 4 * half;   // i_local
        tt[rowl * 40 + l31] = (_Float16)acc[reg];           // [i][o]
    }
    // same-wave LDS write->read: no cross-wave barrier needed
    int orow = lane >> 1;
    int li = (lane & 1) * 16;
    half8 h0, h1;
#pragma unroll
    for (int t = 0; t < 8; ++t) h0[t] = tt[(li + t) * 40 + orow];
#pragma unroll
    for (int t = 0; t < 8; ++t) h1[t] = tt[(li + 8 + t) * 40 + orow];
    _Float16* op = hT + (long)(o0 + wc * 32 + orow) * NROW + i0 + wr * 32 + li;
    *reinterpret_cast<half8*>(op) = h0;
    *reinterpret_cast<half8*>(op + 8) = h1;

    // fused edges: row l31, d-slice [wc*32 + half*16, +16)
    half8 hv0 = *reinterpret_cast<const half8*>(tt + l31 * 40 + half * 16);
    half8 hv1 = *reinterpret_cast<const half8*>(tt + l31 * 40 + half * 16 + 8);
    const float* ap = a_src + head * ND + wc * 32 + half * 16;
    const float* dp = a_dst + head * ND + wc * 32 + half * 16;
    float4 as0 = *reinterpret_cast<const float4*>(ap);
    float4 as1 = *reinterpret_cast<const float4*>(ap + 4);
    float4 as2 = *reinterpret_cast<const float4*>(ap + 8);
    float4 as3 = *reinterpret_cast<const float4*>(ap + 12);
    float4 ad0 = *reinterpret_cast<const float4*>(dp);
    float4 ad1 = *reinterpret_cast<const float4*>(dp + 4);
    float4 ad2 = *reinterpret_cast<const float4*>(dp + 8);
    float4 ad3 = *reinterpret_cast<const float4*>(dp + 12);
    float ps = 0.f, pd = 0.f;
    ps += (float)hv0[0]*as0.x + (float)hv0[1]*as0.y + (float)hv0[2]*as0.z + (float)hv0[3]*as0.w;
    ps += (float)hv0[4]*as1.x + (float)hv0[5]*as1.y + (float)hv0[6]*as1.z + (float)hv0[7]*as1.w;
    ps += (float)hv1[0]*as2.x + (float)hv1[1]*as2.y + (float)hv1[2]*as2.z + (float)hv1[3]*as2.w;
    ps += (float)hv1[4]*as3.x + (float)hv1[5]*as3.y + (float)hv1[6]*as3.z + (float)hv1[7]*as3.w;
    pd += (float)hv0[0]*ad0.x + (float)hv0[1]*ad0.y + (float)hv0[2]*ad0.z + (float)hv0[3]*ad0.w;
    pd += (float)hv0[4]*ad1.x + (float)hv0[5]*ad1.y + (float)hv0[6]*ad1.z + (float)hv0[7]*ad1.w;
    pd += (float)hv1[0]*ad2.x + (float)hv1[1]*ad2.y + (float)hv1[2]*ad2.z + (float)hv1[3]*ad2.w;
    pd += (float)hv1[4]*ad3.x + (float)hv1[5]*ad3.y + (float)hv1[6]*ad3.z + (float)hv1[7]*ad3.w;
    ps += __shfl_xor(ps, 32, 64);   // combine d half-slices
    pd += __shfl_xor(pd, 32, 64);
    if (half == 0) { ered[0][wr][wc][l31] = ps; ered[1][wr][wc][l31] = pd; }
    __syncthreads();
    if (wc == 0) {
        float pst = ered[0][wr][0][l31] + ered[0][wr][1][l31];
        float pdt = ered[1][wr][0][l31] + ered[1][wr][1][l31];
        if (half == 0) {
            e_srcT[head * NROW + i0 + wr * 32 + l31] = pst;
            e_dstT[head * NROW + i0 + wr * 32 + l31] = pdt;
        }
        float mx = pdt;
#pragma unroll
        for (int off = 1; off < 32; off <<= 1) mx = fmaxf(mx, __shfl_xor(mx, off, 64));
        if (lane == 0) atomicMax(&maxkey[head], gat_enc_key(mx));
    }
}

// ---------------------------------------------------------------------------
// Stage 3: masked softmax-PV, 32x32x16 FP16 MFMA, packed-f16 p-compute.
// THIS ROUND: 256-row i-blocks — each wave owns TWO 32-row tiles (A at
// i0+wave*32, B at +128) sharing the same staged j-data: P/Q LDS reads,
// hbuf staging and v0/v1 ds_reads are all amortized 2x. Halves the hT
// staging traffic (72 -> 36 MB of L3 re-reads). Per tile: unscaled
// af = max(P_j, Q_j * R_i) * mask (A_i cancels in num/den); mask via 64-bit
// interleaved sign-spread; den on MFMA pipe via ones-B.
// Grid: 12 ig x 4 jc x 8 heads = 384 blocks, 256 thr.
// ---------------------------------------------------------------------------
__global__ __launch_bounds__(256) void gat_attn(const unsigned* __restrict__ bits,
                                                const float* __restrict__ e_srcT,
                                                const float* __restrict__ e_dstT,
                                                const unsigned* __restrict__ maxkey,
                                                const _Float16* __restrict__ hT,
                                                _Float16* __restrict__ num,
                                                float* __restrict__ den) {
    constexpr int JCHUNK = NROW / 4;         // 768
    constexpr int NC = JCHUNK / 64;          // 12 chunks of 64 j
    __shared__ unsigned lds_P[JCHUNK / 2];               // 1.5 KB (half2 pairs)
    __shared__ unsigned lds_Q[JCHUNK / 2];               // 1.5 KB
    __shared__ __align__(16) _Float16 hbuf[2][4096];     // 2 x 8 KB
    int b = blockIdx.x;
    int head = b & 7;
    int jc = (b >> 3) & 3;
    int i0 = (b >> 5) * 256;
    int jbase = jc * JCHUNK;
    int tid = threadIdx.x;
    int wave = tid >> 6;
    int lane = tid & 63;
    int half = lane >> 5;
    int l31 = lane & 31;

    float Mg = gat_dec_key(maxkey[head]);
    for (int p = tid; p < JCHUNK / 2; p += 256) {
        float t0 = e_dstT[head * NROW + jbase + 2 * p] - Mg;      // <= 0
        float t1 = e_dstT[head * NROW + jbase + 2 * p + 1] - Mg;
        half2v P = { (_Float16)__expf(t0), (_Float16)__expf(t1) };
        half2v Q = { (_Float16)__expf(0.2f * t0), (_Float16)__expf(0.2f * t1) };
        lds_P[p] = __builtin_bit_cast(unsigned, P);
        lds_Q[p] = __builtin_bit_cast(unsigned, Q);
    }

    int irowA = i0 + wave * 32 + l31;
    int irowB = irowA + 128;
    float uA = e_srcT[head * NROW + irowA] + Mg;
    float uB = e_srcT[head * NROW + irowB] + Mg;
    float RfA = fminf(__expf(-0.8f * uA), 60000.f);
    float RfB = fminf(__expf(-0.8f * uB), 60000.f);
    _Float16 RhA = (_Float16)RfA, RhB = (_Float16)RfB;
    half2v R2A = { RhA, RhA };
    half2v R2B = { RhB, RhB };
    const half8 ones8 = { (_Float16)1.f, (_Float16)1.f, (_Float16)1.f, (_Float16)1.f,
                          (_Float16)1.f, (_Float16)1.f, (_Float16)1.f, (_Float16)1.f };
    const unsigned* browA = bits + (long)irowA * 96 + jc * (JCHUNK / 32);
    const unsigned* browB = bits + (long)irowB * 96 + jc * (JCHUNK / 32);

    // staging: 512 slots of 16 B; slot s: js=s>>7, dh=(s>>6)&1, sl=s&63;
    // thread t stages slots t and t+256.
    int s0 = tid, s1 = tid + 256;
    const _Float16* gp0 = hT + (head * ND + ((s0 >> 6) & 1) * 32 + (s0 & 31)) * NROW
                             + jbase + (s0 >> 7) * 16 + ((s0 >> 5) & 1) * 8;
    const _Float16* gp1 = hT + (head * ND + ((s1 >> 6) & 1) * 32 + (s1 & 31)) * NROW
                             + jbase + (s1 >> 7) * 16 + ((s1 >> 5) & 1) * 8;
    *reinterpret_cast<half8*>(&hbuf[0][tid * 8])         = *reinterpret_cast<const half8*>(gp0);
    *reinterpret_cast<half8*>(&hbuf[0][(tid + 256) * 8]) = *reinterpret_cast<const half8*>(gp1);
    __syncthreads();

    f32x16 acc0a = {}, acc1a = {}, acc2a = {};
    f32x16 acc0b = {}, acc1b = {}, acc2b = {};
    uint2 wmA = *reinterpret_cast<const uint2*>(browA);
    uint2 wmB = *reinterpret_cast<const uint2*>(browB);

    for (int k = 0; k < NC; ++k) {
        half8 st0, st1;
        uint2 wmnA = wmA, wmnB = wmB;
        bool more = (k + 1 < NC);
        if (more) {
            st0 = *reinterpret_cast<const half8*>(gp0 + (k + 1) * 64);
            st1 = *reinterpret_cast<const half8*>(gp1 + (k + 1) * 64);
            wmnA = *reinterpret_cast<const uint2*>(browA + (k + 1) * 2);
            wmnB = *reinterpret_cast<const uint2*>(browB + (k + 1) * 2);
        }
        const _Float16* hb = &hbuf[k & 1][0];
#pragma unroll
        for (int js = 0; js < 4; ++js) {
            int sh = (js & 1) * 16 + half * 8;
            unsigned w8A = (((js < 2) ? wmA.x : wmA.y) >> sh) & 0xffu;
            unsigned w8B = (((js < 2) ? wmB.x : wmB.y) >> sh) & 0xffu;
            unsigned long long S64A = ((unsigned long long)(w8A & 0x55u) << 15)
                                    | ((unsigned long long)(w8A & 0xAAu) << 30);
            unsigned long long S64B = ((unsigned long long)(w8B & 0x55u) << 15)
                                    | ((unsigned long long)(w8B & 0xAAu) << 30);
            uint4 Pv = *reinterpret_cast<const uint4*>(&lds_P[k * 32 + js * 8 + half * 4]);
            uint4 Qv = *reinterpret_cast<const uint4*>(&lds_Q[k * 32 + js * 8 + half * 4]);
            unsigned pr[4] = { Pv.x, Pv.y, Pv.z, Pv.w };
            unsigned qr[4] = { Qv.x, Qv.y, Qv.z, Qv.w };
            unsigned amA[4], amB[4];
#pragma unroll
            for (int t = 0; t < 4; ++t) {
                half2v pv = __builtin_bit_cast(half2v, pr[t]);
                half2v qv = __builtin_bit_cast(half2v, qr[t]);
                half2v mxA = __builtin_elementwise_max(pv, qv * R2A);          // pk_mul+pk_max
                half2v mxB = __builtin_elementwise_max(pv, qv * R2B);
                s16x2 mkA = __builtin_bit_cast(s16x2, (unsigned)(S64A >> (2 * t))) >> 15;
                s16x2 mkB = __builtin_bit_cast(s16x2, (unsigned)(S64B >> (2 * t))) >> 15;
                amA[t] = __builtin_bit_cast(unsigned, mxA) & __builtin_bit_cast(unsigned, mkA);
                amB[t] = __builtin_bit_cast(unsigned, mxB) & __builtin_bit_cast(unsigned, mkB);
            }
            uint4 m4a = { amA[0], amA[1], amA[2], amA[3] };
            uint4 m4b = { amB[0], amB[1], amB[2], amB[3] };
            half8 afA = __builtin_bit_cast(half8, m4a);                        // free repack
            half8 afB = __builtin_bit_cast(half8, m4b);
            half8 v0 = *reinterpret_cast<const half8*>(hb + (js * 128 + lane) * 8);
            half8 v1 = *reinterpret_cast<const half8*>(hb + (js * 128 + 64 + lane) * 8);
            acc0a = __builtin_amdgcn_mfma_f32_32x32x16_f16(afA, v0, acc0a, 0, 0, 0);
            acc1a = __builtin_amdgcn_mfma_f32_32x32x16_f16(afA, v1, acc1a, 0, 0, 0);
            acc2a = __builtin_amdgcn_mfma_f32_32x32x16_f16(afA, ones8, acc2a, 0, 0, 0);
            acc0b = __builtin_amdgcn_mfma_f32_32x32x16_f16(afB, v0, acc0b, 0, 0, 0);
            acc1b = __builtin_amdgcn_mfma_f32_32x32x16_f16(afB, v1, acc1b, 0, 0, 0);
            acc2b = __builtin_amdgcn_mfma_f32_32x32x16_f16(afB, ones8, acc2b, 0, 0, 0);
        }
        if (more) {
            *reinterpret_cast<half8*>(&hbuf[(k + 1) & 1][tid * 8])         = st0;
            *reinterpret_cast<half8*>(&hbuf[(k + 1) & 1][(tid + 256) * 8]) = st1;
        }
        wmA = wmnA;
        wmB = wmnB;
        __syncthreads();
    }

    // epilogue: den from acc2 ones-column, num stores (A_i cancels -> no scale).
#pragma unroll
    for (int reg = 0; reg < 16; ++reg) {
        int rowl = (reg & 3) + 8 * (reg >> 2) + 4 * half;
        long rbaseA = (long)(jc * NROW + i0 + wave * 32 + rowl);
        long rbaseB = rbaseA + 128;
        if (l31 == 0) {
            den[rbaseA * NH + head] = acc2a[reg];
            den[rbaseB * NH + head] = acc2b[reg];
        }
        long obA = rbaseA * NF + head * ND + l31;
        long obB = rbaseB * NF + head * ND + l31;
        num[obA]      = (_Float16)acc0a[reg];
        num[obA + 32] = (_Float16)acc1a[reg];
        num[obB]      = (_Float16)acc0b[reg];
        num[obB + 32] = (_Float16)acc1b[reg];
    }
}

// ---------------------------------------------------------------------------
// Stage 4: out[i,c..c+7] = sum_jc num[jc][i][c..] / sum_jc den[jc][i][c>>6]
// Vectorized: one thread = 8 consecutive c (half8 loads, float4 stores).
// Grid 768 x 256.
// ---------------------------------------------------------------------------
__global__ __launch_bounds__(256) void gat_final(const _Float16* __restrict__ num,
                                                 const float* __restrict__ den,
                                                 float* __restrict__ out) {
    int idx = (blockIdx.x * 256 + threadIdx.x) * 8;   // 0 .. NROW*NF step 8
    int i = idx >> 9;
    int c = idx & 511;
    int head = c >> 6;
    half8 n0 = *reinterpret_cast<const half8*>(num + (long)i * NF + c);
    half8 n1 = *reinterpret_cast<const half8*>(num + (long)(NROW + i) * NF + c);
    half8 n2 = *reinterpret_cast<const half8*>(num + (long)(2 * NROW + i) * NF + c);
    half8 n3 = *reinterpret_cast<const half8*>(num + (long)(3 * NROW + i) * NF + c);
    float ds = den[i * NH + head] + den[(NROW + i) * NH + head]
             + den[(2 * NROW + i) * NH + head] + den[(3 * NROW + i) * NH + head];
    float inv = 1.0f / fmaxf(ds, 1e-30f);
    float r0 = ((float)n0[0] + (float)n1[0] + (float)n2[0] + (float)n3[0]) * inv;
    float r1 = ((float)n0[1] + (float)n1[1] + (float)n2[1] + (float)n3[1]) * inv;
    float r2 = ((float)n0[2] + (float)n1[2] + (float)n2[2] + (float)n3[2]) * inv;
    float r3 = ((float)n0[3] + (float)n1[3] + (float)n2[3] + (float)n3[3]) * inv;
    float r4 = ((float)n0[4] + (float)n1[4] + (float)n2[4] + (float)n3[4]) * inv;
    float r5 = ((float)n0[5] + (float)n1[5] + (float)n2[5] + (float)n3[5]) * inv;
    float r6 = ((float)n0[6] + (float)n1[6] + (float)n2[6] + (float)n3[6]) * inv;
    float r7 = ((float)n0[7] + (float)n1[7] + (float)n2[7] + (float)n3[7]) * inv;
    float4 o0 = { r0, r1, r2, r3 };
    float4 o1 = { r4, r5, r6, r7 };
    *reinterpret_cast<float4*>(out + idx)     = o0;
    *reinterpret_cast<float4*>(out + idx + 4) = o1;
}

// ---------------------------------------------------------------------------
extern "C" void kernel_launch(void* const* d_in, const int* in_sizes, int n_in,
                              void* d_out, int out_size, void* d_ws, size_t ws_size,
                              hipStream_t stream) {
    const float* x_raw  = (const float*)d_in[0];
    const int*   adj    = (const int*)d_in[1];
    const float* W_raw  = (const float*)d_in[2];
    const float* as_raw = (const float*)d_in[3];
    const float* ad_raw = (const float*)d_in[4];
    float* out = (float*)d_out;

    char* ws = (char*)d_ws;
    _Float16* hT     = (_Float16*)(ws);                  // 3,145,728 B
    float*    e_srcT = (float*)(ws + 3145728);           //    98,304 B
    float*    e_dstT = (float*)(ws + 3244032);           //    98,304 B
    unsigned* maxkey = (unsigned*)(ws + 3342336);        //        64 B
    unsigned* bits   = (unsigned*)(ws + 3342400);        // 1,179,648 B
    _Float16* num    = (_Float16*)(ws + 8192064);        // 12,582,912 B (f16)
    float*    den    = (float*)(ws + 20774976);          //   393,216 B
    // total 21,168,192 B (<= previously-verified capacity)

    hipMemsetAsync(maxkey, 0, 64, stream);
    gat_gemm_bp<<<BP_BLOCKS + GEMM_BLOCKS, 256, 0, stream>>>(x_raw, W_raw, hT, adj,
                                                             (unsigned long long*)bits,
                                                             as_raw, ad_raw,
                                                             e_srcT, e_dstT, maxkey);
    gat_attn<<<12 * 4 * 8, 256, 0, stream>>>(bits, e_srcT, e_dstT, maxkey, hT, num, den);
    gat_final<<<NROW * NF / 2048, 256, 0, stream>>>(num, den, out);
}